// Round 5
// baseline (350.937 us; speedup 1.0000x reference)
//
#include <hip/hip_runtime.h>
#include <hip/hip_bf16.h>
#include <math.h>

// Problem constants (from reference)
#define GRU_H 256
#define H1D   128
#define H2D   64
#define BB    16
#define TT    4000
#define NN    320000   // T * HOP

typedef __attribute__((ext_vector_type(8))) short short8;
typedef __attribute__((ext_vector_type(4))) float f32x4;

static __device__ __forceinline__ unsigned short f2bf(float x) {
    unsigned u = __float_as_uint(x);
    return (unsigned short)((u + 0x7FFFu + ((u >> 16) & 1u)) >> 16);
}
static __device__ __forceinline__ float bf2f(unsigned short h) {
    return __uint_as_float(((unsigned)h) << 16);
}

// ---------------- K1: bf16-MFMA MLP -> ratio[B*T] -----------------------
// (unchanged from R4 except: block 0 zeroes 3 ws slots incl. barrier ctr)
#define H1CH 4608   // 128*36
#define W2CH 2304   // 64*36
__global__ __launch_bounds__(256) void mlp_kernel(
    const float* __restrict__ gru, const float* __restrict__ W1,
    const float* __restrict__ b1,  const float* __restrict__ a1p,
    const float* __restrict__ W2,  const float* __restrict__ b2,
    const float* __restrict__ a2p, const float* __restrict__ W3,
    const float* __restrict__ b3,  float* __restrict__ ratio_out,
    unsigned* __restrict__ ws_u)
{
    __shared__ unsigned short smem[36864];
    __shared__ float w3f[64];
    unsigned short* As  = smem;
    unsigned short* Bs  = smem + 4608;
    unsigned short* h2s = smem;          // overlays As/Bs (safe: after layer 1)
    unsigned short* h1s = smem + 9216;
    unsigned short* W2s = smem + 27648;

    const int t    = threadIdx.x;
    const int wave = t >> 6, lane = t & 63;
    const int lr   = lane & 15, q = lane >> 4;
    const int m0   = blockIdx.x * 128;
    const float a1v = a1p[0], a2v = a2p[0];

    if (blockIdx.x == 0 && t < 3) ws_u[t] = 0u;   // maxes + barrier counter
    if (t < 64) w3f[t] = W3[2 * H2D + t];         // only row 2 of W3 is live

    // ================= layer 1: h1 = prelu(G @ W1^T + b1) ===============
    const int wr = wave >> 1;
    const int wc = wave & 1;
    f32x4 acc1[4][4];
    #pragma unroll
    for (int mi = 0; mi < 4; ++mi)
        #pragma unroll
        for (int ni = 0; ni < 4; ++ni) acc1[mi][ni] = (f32x4){0.f, 0.f, 0.f, 0.f};

    for (int kc = 0; kc < 8; ++kc) {
        const int k0 = kc * 32;
        __syncthreads();
        #pragma unroll
        for (int it = 0; it < 4; ++it) {
            const int idx = t + 256 * it;
            const int row = idx >> 3, c4 = idx & 7;
            float4 g = *(const float4*)(gru + (size_t)(m0 + row) * GRU_H + k0 + c4 * 4);
            ushort4 gh = {f2bf(g.x), f2bf(g.y), f2bf(g.z), f2bf(g.w)};
            *(ushort4*)(As + row * 36 + c4 * 4) = gh;
            float4 w = *(const float4*)(W1 + (size_t)row * GRU_H + k0 + c4 * 4);
            ushort4 wh = {f2bf(w.x), f2bf(w.y), f2bf(w.z), f2bf(w.w)};
            *(ushort4*)(Bs + row * 36 + c4 * 4) = wh;
        }
        __syncthreads();
        short8 af[4], bf[4];
        #pragma unroll
        for (int mi = 0; mi < 4; ++mi) {
            const unsigned short* p = As + (wr * 64 + mi * 16 + lr) * 36 + q * 8;
            ushort4 lo = *(const ushort4*)(p), hi = *(const ushort4*)(p + 4);
            af[mi] = (short8){(short)lo.x, (short)lo.y, (short)lo.z, (short)lo.w,
                              (short)hi.x, (short)hi.y, (short)hi.z, (short)hi.w};
        }
        #pragma unroll
        for (int ni = 0; ni < 4; ++ni) {
            const unsigned short* p = Bs + (wc * 64 + ni * 16 + lr) * 36 + q * 8;
            ushort4 lo = *(const ushort4*)(p), hi = *(const ushort4*)(p + 4);
            bf[ni] = (short8){(short)lo.x, (short)lo.y, (short)lo.z, (short)lo.w,
                              (short)hi.x, (short)hi.y, (short)hi.z, (short)hi.w};
        }
        #pragma unroll
        for (int mi = 0; mi < 4; ++mi)
            #pragma unroll
            for (int ni = 0; ni < 4; ++ni)
                acc1[mi][ni] = __builtin_amdgcn_mfma_f32_16x16x32_bf16(
                    af[mi], bf[ni], acc1[mi][ni], 0, 0, 0);
    }

    #pragma unroll
    for (int ni = 0; ni < 4; ++ni) {
        const int col = wc * 64 + ni * 16 + lr;
        const float bv = b1[col];
        unsigned short* dst = h1s + (col >> 5) * H1CH + (col & 31);
        #pragma unroll
        for (int mi = 0; mi < 4; ++mi) {
            const int rbase = wr * 64 + mi * 16 + q * 4;
            #pragma unroll
            for (int r = 0; r < 4; ++r) {
                float x = acc1[mi][ni][r] + bv;
                x = (x >= 0.f) ? x : a1v * x;
                dst[(rbase + r) * 36] = f2bf(x);
            }
        }
    }
    #pragma unroll
    for (int it = 0; it < 8; ++it) {
        const int idx = t + 256 * it;
        const int row = idx >> 5, c4 = idx & 31;
        float4 w = *(const float4*)(W2 + (size_t)row * H1D + c4 * 4);
        ushort4 wh = {f2bf(w.x), f2bf(w.y), f2bf(w.z), f2bf(w.w)};
        *(ushort4*)(W2s + (c4 >> 3) * W2CH + row * 36 + (c4 & 7) * 4) = wh;
    }
    __syncthreads();

    // ================= layer 2 ==========================================
    const int wr2 = wave >> 1;
    const int wc2 = wave & 1;
    f32x4 acc2[4][2];
    #pragma unroll
    for (int mi = 0; mi < 4; ++mi)
        #pragma unroll
        for (int ni = 0; ni < 2; ++ni) acc2[mi][ni] = (f32x4){0.f, 0.f, 0.f, 0.f};

    #pragma unroll
    for (int kc = 0; kc < 4; ++kc) {
        short8 af[4], bf[2];
        #pragma unroll
        for (int mi = 0; mi < 4; ++mi) {
            const unsigned short* p = h1s + kc * H1CH + (wr2 * 64 + mi * 16 + lr) * 36 + q * 8;
            ushort4 lo = *(const ushort4*)(p), hi = *(const ushort4*)(p + 4);
            af[mi] = (short8){(short)lo.x, (short)lo.y, (short)lo.z, (short)lo.w,
                              (short)hi.x, (short)hi.y, (short)hi.z, (short)hi.w};
        }
        #pragma unroll
        for (int ni = 0; ni < 2; ++ni) {
            const unsigned short* p = W2s + kc * W2CH + (wc2 * 32 + ni * 16 + lr) * 36 + q * 8;
            ushort4 lo = *(const ushort4*)(p), hi = *(const ushort4*)(p + 4);
            bf[ni] = (short8){(short)lo.x, (short)lo.y, (short)lo.z, (short)lo.w,
                              (short)hi.x, (short)hi.y, (short)hi.z, (short)hi.w};
        }
        #pragma unroll
        for (int mi = 0; mi < 4; ++mi)
            #pragma unroll
            for (int ni = 0; ni < 2; ++ni)
                acc2[mi][ni] = __builtin_amdgcn_mfma_f32_16x16x32_bf16(
                    af[mi], bf[ni], acc2[mi][ni], 0, 0, 0);
    }

    #pragma unroll
    for (int ni = 0; ni < 2; ++ni) {
        const int col = wc2 * 32 + ni * 16 + lr;
        const float bv = b2[col];
        unsigned short* dst = h2s + (col >> 5) * H1CH + (col & 31);
        #pragma unroll
        for (int mi = 0; mi < 4; ++mi) {
            const int rbase = wr2 * 64 + mi * 16 + q * 4;
            #pragma unroll
            for (int r = 0; r < 4; ++r) {
                float x = acc2[mi][ni][r] + bv;
                x = (x >= 0.f) ? x : a2v * x;
                dst[(rbase + r) * 36] = f2bf(x);
            }
        }
    }
    __syncthreads();

    // ================= layer 3 (p2 only) + softplus + clip ==============
    if (t < 128) {
        float p = b3[2];
        #pragma unroll
        for (int k = 0; k < 64; ++k)
            p = fmaf(bf2f(h2s[(k >> 5) * H1CH + t * 36 + (k & 31)]), w3f[k], p);
        float sp = fmaxf(p, 0.f) + log1pf(expf(-fabsf(p)));
        ratio_out[m0 + t] = fminf(sp + 1.0f, 20.0f);
    }
}

// ---------------- K2: wave-scan IIR compressor + fused normalize --------
// R5 changes vs R4: (1) chunk e/x loads software-pipelined one chunk ahead;
// (2) ratio window (<=22 entries/segment) preloaded into lanes, interp via
// ds_bpermute instead of per-sample global loads; (3) outputs kept in
// registers, hand-rolled device-scope grid barrier (1000 blocks co-resident:
// __launch_bounds__(256,4) -> <=128 VGPR -> >=4 blocks/CU, capacity 8),
// then scale applied in-register and stored once (kills scale_kernel and
// its 41 MB extra traffic).
#define CH     256
#define SEGCH  5
#define SEGLEN (CH * SEGCH)      // 1280
#define SPR    (NN / SEGLEN)     // 250 (exact)
#define NBLK   (BB * SPR / 4)    // 1000

__global__ __launch_bounds__(256, 4) void compress_kernel(
    const float* __restrict__ enh_g, const float* __restrict__ noi_g,
    const float* __restrict__ ratio, float* __restrict__ out,
    unsigned* __restrict__ ws_u)
{
    const int lane = threadIdx.x & 63;
    const int wid  = blockIdx.x * 4 + (threadIdx.x >> 6);   // 0..3999
    const int row  = wid / SPR;
    const int seg  = wid - row * SPR;
    const int s0   = seg * SEGLEN;

    const float* __restrict__ enh  = enh_g + (size_t)row * NN;
    const float* __restrict__ noi  = noi_g + (size_t)row * NN;
    const float* __restrict__ rrow = ratio + row * TT;
    float* __restrict__ orow       = out   + (size_t)row * NN;

    // ---- preload ratio window: segment touches i0 in [base, base+21] ----
    const float bsrc = fmaf((float)(s0 - CH) + 0.5f, 0.0125f, -0.5f);
    int base = (int)floorf(bsrc);
    if (base < 0) base = 0;
    const float rv = rrow[min(base + lane, TT - 1)];   // lanes 0..31 used

    // d_lane = 0.9^(4*lane)
    float d_lane = 1.f;
    if (lane & 1)  d_lane *= 0.65610000f;
    if (lane & 2)  d_lane *= 0.43046721f;
    if (lane & 4)  d_lane *= 0.18530202f;
    if (lane & 8)  d_lane *= 0.034336838f;
    if (lane & 16) d_lane *= 0.0011790185f;
    if (lane & 32) d_lane *= 1.3900845e-06f;

    // ---- preload chunk 0 (warmup) ----
    {
    }
    const int p0w = s0 - CH + 4 * lane;
    const int pcw = p0w < 0 ? 0 : p0w;
    float4 e_cur = *(const float4*)(enh + pcw);
    float4 x_cur = *(const float4*)(noi + pcw);

    float s_e = 0.f, s_r = 0.f;
    float amax_c = 0.f, amax_e = 0.f;
    float cbuf[SEGCH][4];

    #pragma unroll
    for (int ci = 0; ci < SEGCH + 1; ++ci) {
        // prefetch next chunk (always in-bounds: base >= s0 >= 0)
        float4 e_nxt, x_nxt;
        if (ci < SEGCH) {
            const int pn = s0 - CH + (ci + 1) * CH + 4 * lane;
            e_nxt = *(const float4*)(enh + pn);
            x_nxt = *(const float4*)(noi + pn);
        }

        const int cb = s0 - CH + ci * CH;     // chunk base (wave-uniform)
        const int p0 = cb + 4 * lane;

        // ---- per-sample gains + lane-local partials ----
        float pe[4], pr[4];
        float ge0 = 0.f, gr0 = 0.f;
        float ae = 0.f, ar = 0.f;
        #pragma unroll
        for (int k = 0; k < 4; ++k) {
            const float e   = (&e_cur.x)[k];
            const float x   = (&x_cur.x)[k];
            const float res = x - e;
            const int n  = p0 + k;
            const int nc = n < 0 ? 0 : n;
            float src = fmaf((float)nc + 0.5f, 0.0125f, -0.5f);
            src = fminf(fmaxf(src, 0.f), 3999.f);
            const int   i0 = (int)src;
            const float w  = src - (float)i0;
            const int   li0 = i0 - base;
            const int   li1 = min(i0 + 1, 3999) - base;
            const float r0 = __shfl(rv, li0, 64);
            const float r1 = __shfl(rv, li1, 64);
            const float rr = r0 * (1.f - w) + r1 * w;
            const float rcp_rr = __builtin_amdgcn_rcpf(rr);

            const float env_e = fabsf(e);
            const float gre = (env_e > 0.3f) ? fmaf(env_e - 0.3f, rcp_rr, 0.3f) : env_e;
            const float ge  = fminf(fmaxf(gre * __builtin_amdgcn_rcpf(env_e + 1e-8f), 0.1f), 2.f);
            const float env_r = fabsf(res);
            const float grr = (env_r > 0.1f) ? fmaf(env_r - 0.1f, 2.f * rcp_rr, 0.1f) : env_r;
            const float gr  = fminf(fmaxf(grr * __builtin_amdgcn_rcpf(env_r + 1e-8f), 0.1f), 2.f);

            if (k == 0) { ge0 = ge; gr0 = gr; }
            ae = fmaf(0.9f, ae, 0.1f * ge);
            ar = fmaf(0.9f, ar, 0.1f * gr);
            pe[k] = ae; pr[k] = ar;
        }

        // ---- Kogge-Stone scan over lanes (constant-a: b-only) ----
        float Be = pe[3], Br = pr[3];
        #pragma unroll
        for (int l = 0; l < 6; ++l) {
            const int dlt = 1 << l;
            const float ml = (l == 0) ? 0.65610000f  :
                             (l == 1) ? 0.43046721f  :
                             (l == 2) ? 0.18530202f  :
                             (l == 3) ? 0.034336838f :
                             (l == 4) ? 0.0011790185f : 1.3900845e-06f;
            const float me  = (lane >= dlt) ? ml : 0.f;
            const float bse = __shfl_up(Be, dlt, 64);
            const float bsr = __shfl_up(Br, dlt, 64);
            Be = fmaf(me, bse, Be);
            Br = fmaf(me, bsr, Br);
        }
        float Ee = __shfl_up(Be, 1, 64); if (lane == 0) Ee = 0.f;
        float Er = __shfl_up(Br, 1, 64); if (lane == 0) Er = 0.f;

        // exact reset at global sample 0 (chunk starting at n=0)
        if (cb == 0) { s_e = __shfl(ge0, 0, 64); s_r = __shfl(gr0, 0, 64); }

        const float Se = fmaf(d_lane, s_e, Ee);
        const float Sr = fmaf(d_lane, s_r, Er);

        if (ci > 0) {   // stored chunk: keep in registers until post-barrier
            #pragma unroll
            for (int k = 0; k < 4; ++k) {
                const float ck = (k == 0) ? 0.9f : (k == 1) ? 0.81f
                               : (k == 2) ? 0.729f : 0.6561f;
                const float sek = fmaf(ck, Se, pe[k]);
                const float srk = fmaf(ck, Sr, pr[k]);
                const float e   = (&e_cur.x)[k];
                const float res = (&x_cur.x)[k] - e;
                const float c   = fmaf(0.1f * res, srk, e * sek);
                cbuf[ci - 1][k] = c;
                amax_c = fmaxf(amax_c, fabsf(c));
                amax_e = fmaxf(amax_e, fabsf(e));
            }
        }

        const float b63e = __shfl(Be, 63, 64);
        const float b63r = __shfl(Br, 63, 64);
        s_e = fmaf(1.9287e-12f, s_e, b63e);
        s_r = fmaf(1.9287e-12f, s_r, b63r);
        e_cur = e_nxt; x_cur = x_nxt;
    }

    // ---- wave -> block -> global max reduction ----
    #pragma unroll
    for (int off = 32; off > 0; off >>= 1) {
        amax_c = fmaxf(amax_c, __shfl_xor(amax_c, off, 64));
        amax_e = fmaxf(amax_e, __shfl_xor(amax_e, off, 64));
    }
    __shared__ float red[8];
    const int wv = threadIdx.x >> 6, ln = threadIdx.x & 63;
    if (ln == 0) { red[wv] = amax_c; red[4 + wv] = amax_e; }
    __syncthreads();
    if (threadIdx.x == 0) {
        float mc = fmaxf(fmaxf(red[0], red[1]), fmaxf(red[2], red[3]));
        float me = fmaxf(fmaxf(red[4], red[5]), fmaxf(red[6], red[7]));
        atomicMax(ws_u + 0, __float_as_uint(mc));
        atomicMax(ws_u + 1, __float_as_uint(me));
    }

    // ---- hand-rolled grid barrier (all NBLK blocks co-resident) ----
    __threadfence();
    if (threadIdx.x == 0) {
        __hip_atomic_fetch_add(ws_u + 2, 1u, __ATOMIC_ACQ_REL, __HIP_MEMORY_SCOPE_AGENT);
        while (__hip_atomic_load(ws_u + 2, __ATOMIC_ACQUIRE, __HIP_MEMORY_SCOPE_AGENT) < NBLK)
            __builtin_amdgcn_s_sleep(8);
    }
    __syncthreads();

    // ---- scale in-register and store once ----
    const float mo = __uint_as_float(
        __hip_atomic_load(ws_u + 0, __ATOMIC_ACQUIRE, __HIP_MEMORY_SCOPE_AGENT));
    const float me = __uint_as_float(
        __hip_atomic_load(ws_u + 1, __ATOMIC_ACQUIRE, __HIP_MEMORY_SCOPE_AGENT));
    const float scale = me / (mo + 1e-8f);
    #pragma unroll
    for (int ci = 0; ci < SEGCH; ++ci) {
        float4 o;
        #pragma unroll
        for (int k = 0; k < 4; ++k) (&o.x)[k] = cbuf[ci][k] * scale;
        *(float4*)(orow + s0 + ci * CH + 4 * lane) = o;
    }
}

extern "C" void kernel_launch(void* const* d_in, const int* in_sizes, int n_in,
                              void* d_out, int out_size, void* d_ws, size_t ws_size,
                              hipStream_t stream) {
    const float* gru = (const float*)d_in[0];
    const float* enh = (const float*)d_in[1];
    const float* noi = (const float*)d_in[2];
    const float* W1  = (const float*)d_in[3];
    const float* b1  = (const float*)d_in[4];
    const float* a1  = (const float*)d_in[5];
    const float* W2  = (const float*)d_in[6];
    const float* b2  = (const float*)d_in[7];
    const float* a2  = (const float*)d_in[8];
    const float* W3  = (const float*)d_in[9];
    const float* b3  = (const float*)d_in[10];
    float* out = (float*)d_out;

    unsigned* ws_u = (unsigned*)d_ws;        // [0]=max|c|, [1]=max|e|, [2]=done ctr
    float* ratio   = (float*)((char*)d_ws + 256);   // B*T floats

    mlp_kernel<<<(BB * TT) / 128, 256, 0, stream>>>(gru, W1, b1, a1, W2, b2, a2, W3, b3, ratio, ws_u);
    compress_kernel<<<NBLK, 256, 0, stream>>>(enh, noi, ratio, out, ws_u);
}

// Round 6
// 216.902 us; speedup vs baseline: 1.6179x; 1.6179x over previous
//
#include <hip/hip_runtime.h>
#include <hip/hip_bf16.h>
#include <math.h>

// Problem constants (from reference)
#define GRU_H 256
#define H1D   128
#define H2D   64
#define BB    16
#define TT    4000
#define NN    320000   // T * HOP

typedef __attribute__((ext_vector_type(8))) short short8;
typedef __attribute__((ext_vector_type(4))) float f32x4;

static __device__ __forceinline__ unsigned short f2bf(float x) {
    unsigned u = __float_as_uint(x);
    return (unsigned short)((u + 0x7FFFu + ((u >> 16) & 1u)) >> 16);
}
static __device__ __forceinline__ float bf2f(unsigned short h) {
    return __uint_as_float(((unsigned)h) << 16);
}

// ---------------- K1: bf16-MFMA MLP -> ratio[B*T] -----------------------
// (unchanged; block 0 zeroes the 2 ws atomic-max slots)
#define H1CH 4608   // 128*36
#define W2CH 2304   // 64*36
__global__ __launch_bounds__(256) void mlp_kernel(
    const float* __restrict__ gru, const float* __restrict__ W1,
    const float* __restrict__ b1,  const float* __restrict__ a1p,
    const float* __restrict__ W2,  const float* __restrict__ b2,
    const float* __restrict__ a2p, const float* __restrict__ W3,
    const float* __restrict__ b3,  float* __restrict__ ratio_out,
    unsigned* __restrict__ ws_u)
{
    __shared__ unsigned short smem[36864];
    __shared__ float w3f[64];
    unsigned short* As  = smem;
    unsigned short* Bs  = smem + 4608;
    unsigned short* h2s = smem;          // overlays As/Bs (safe: after layer 1)
    unsigned short* h1s = smem + 9216;
    unsigned short* W2s = smem + 27648;

    const int t    = threadIdx.x;
    const int wave = t >> 6, lane = t & 63;
    const int lr   = lane & 15, q = lane >> 4;
    const int m0   = blockIdx.x * 128;
    const float a1v = a1p[0], a2v = a2p[0];

    if (blockIdx.x == 0 && t < 2) ws_u[t] = 0u;   // atomic-max slots
    if (t < 64) w3f[t] = W3[2 * H2D + t];         // only row 2 of W3 is live

    // ================= layer 1: h1 = prelu(G @ W1^T + b1) ===============
    const int wr = wave >> 1;
    const int wc = wave & 1;
    f32x4 acc1[4][4];
    #pragma unroll
    for (int mi = 0; mi < 4; ++mi)
        #pragma unroll
        for (int ni = 0; ni < 4; ++ni) acc1[mi][ni] = (f32x4){0.f, 0.f, 0.f, 0.f};

    for (int kc = 0; kc < 8; ++kc) {
        const int k0 = kc * 32;
        __syncthreads();
        #pragma unroll
        for (int it = 0; it < 4; ++it) {
            const int idx = t + 256 * it;
            const int row = idx >> 3, c4 = idx & 7;
            float4 g = *(const float4*)(gru + (size_t)(m0 + row) * GRU_H + k0 + c4 * 4);
            ushort4 gh = {f2bf(g.x), f2bf(g.y), f2bf(g.z), f2bf(g.w)};
            *(ushort4*)(As + row * 36 + c4 * 4) = gh;
            float4 w = *(const float4*)(W1 + (size_t)row * GRU_H + k0 + c4 * 4);
            ushort4 wh = {f2bf(w.x), f2bf(w.y), f2bf(w.z), f2bf(w.w)};
            *(ushort4*)(Bs + row * 36 + c4 * 4) = wh;
        }
        __syncthreads();
        short8 af[4], bf[4];
        #pragma unroll
        for (int mi = 0; mi < 4; ++mi) {
            const unsigned short* p = As + (wr * 64 + mi * 16 + lr) * 36 + q * 8;
            ushort4 lo = *(const ushort4*)(p), hi = *(const ushort4*)(p + 4);
            af[mi] = (short8){(short)lo.x, (short)lo.y, (short)lo.z, (short)lo.w,
                              (short)hi.x, (short)hi.y, (short)hi.z, (short)hi.w};
        }
        #pragma unroll
        for (int ni = 0; ni < 4; ++ni) {
            const unsigned short* p = Bs + (wc * 64 + ni * 16 + lr) * 36 + q * 8;
            ushort4 lo = *(const ushort4*)(p), hi = *(const ushort4*)(p + 4);
            bf[ni] = (short8){(short)lo.x, (short)lo.y, (short)lo.z, (short)lo.w,
                              (short)hi.x, (short)hi.y, (short)hi.z, (short)hi.w};
        }
        #pragma unroll
        for (int mi = 0; mi < 4; ++mi)
            #pragma unroll
            for (int ni = 0; ni < 4; ++ni)
                acc1[mi][ni] = __builtin_amdgcn_mfma_f32_16x16x32_bf16(
                    af[mi], bf[ni], acc1[mi][ni], 0, 0, 0);
    }

    #pragma unroll
    for (int ni = 0; ni < 4; ++ni) {
        const int col = wc * 64 + ni * 16 + lr;
        const float bv = b1[col];
        unsigned short* dst = h1s + (col >> 5) * H1CH + (col & 31);
        #pragma unroll
        for (int mi = 0; mi < 4; ++mi) {
            const int rbase = wr * 64 + mi * 16 + q * 4;
            #pragma unroll
            for (int r = 0; r < 4; ++r) {
                float x = acc1[mi][ni][r] + bv;
                x = (x >= 0.f) ? x : a1v * x;
                dst[(rbase + r) * 36] = f2bf(x);
            }
        }
    }
    #pragma unroll
    for (int it = 0; it < 8; ++it) {
        const int idx = t + 256 * it;
        const int row = idx >> 5, c4 = idx & 31;
        float4 w = *(const float4*)(W2 + (size_t)row * H1D + c4 * 4);
        ushort4 wh = {f2bf(w.x), f2bf(w.y), f2bf(w.z), f2bf(w.w)};
        *(ushort4*)(W2s + (c4 >> 3) * W2CH + row * 36 + (c4 & 7) * 4) = wh;
    }
    __syncthreads();

    // ================= layer 2 ==========================================
    const int wr2 = wave >> 1;
    const int wc2 = wave & 1;
    f32x4 acc2[4][2];
    #pragma unroll
    for (int mi = 0; mi < 4; ++mi)
        #pragma unroll
        for (int ni = 0; ni < 2; ++ni) acc2[mi][ni] = (f32x4){0.f, 0.f, 0.f, 0.f};

    #pragma unroll
    for (int kc = 0; kc < 4; ++kc) {
        short8 af[4], bf[2];
        #pragma unroll
        for (int mi = 0; mi < 4; ++mi) {
            const unsigned short* p = h1s + kc * H1CH + (wr2 * 64 + mi * 16 + lr) * 36 + q * 8;
            ushort4 lo = *(const ushort4*)(p), hi = *(const ushort4*)(p + 4);
            af[mi] = (short8){(short)lo.x, (short)lo.y, (short)lo.z, (short)lo.w,
                              (short)hi.x, (short)hi.y, (short)hi.z, (short)hi.w};
        }
        #pragma unroll
        for (int ni = 0; ni < 2; ++ni) {
            const unsigned short* p = W2s + kc * W2CH + (wc2 * 32 + ni * 16 + lr) * 36 + q * 8;
            ushort4 lo = *(const ushort4*)(p), hi = *(const ushort4*)(p + 4);
            bf[ni] = (short8){(short)lo.x, (short)lo.y, (short)lo.z, (short)lo.w,
                              (short)hi.x, (short)hi.y, (short)hi.z, (short)hi.w};
        }
        #pragma unroll
        for (int mi = 0; mi < 4; ++mi)
            #pragma unroll
            for (int ni = 0; ni < 2; ++ni)
                acc2[mi][ni] = __builtin_amdgcn_mfma_f32_16x16x32_bf16(
                    af[mi], bf[ni], acc2[mi][ni], 0, 0, 0);
    }

    #pragma unroll
    for (int ni = 0; ni < 2; ++ni) {
        const int col = wc2 * 32 + ni * 16 + lr;
        const float bv = b2[col];
        unsigned short* dst = h2s + (col >> 5) * H1CH + (col & 31);
        #pragma unroll
        for (int mi = 0; mi < 4; ++mi) {
            const int rbase = wr2 * 64 + mi * 16 + q * 4;
            #pragma unroll
            for (int r = 0; r < 4; ++r) {
                float x = acc2[mi][ni][r] + bv;
                x = (x >= 0.f) ? x : a2v * x;
                dst[(rbase + r) * 36] = f2bf(x);
            }
        }
    }
    __syncthreads();

    // ================= layer 3 (p2 only) + softplus + clip ==============
    if (t < 128) {
        float p = b3[2];
        #pragma unroll
        for (int k = 0; k < 64; ++k)
            p = fmaf(bf2f(h2s[(k >> 5) * H1CH + t * 36 + (k & 31)]), w3f[k], p);
        float sp = fmaxf(p, 0.f) + log1pf(expf(-fabsf(p)));
        ratio_out[m0 + t] = fminf(sp + 1.0f, 20.0f);
    }
}

// ---------------- K2: wave-scan IIR compressor --------------------------
// R6: barrier fusion REVERTED (R5 post-mortem: 1000-block cross-XCD spin
// barrier cost ~180 µs — probe storm starves the arrival RMWs). Structure
// back to R4 (write unscaled + separate scale pass), with two R5 keepers:
// chunk prefetch and shfl-broadcast ratio. New: SEGCH 5->2 (SEGLEN 512) for
// 2.5x wave parallelism (10000 waves) against the latency-bound diagnosis
// (R4: VALUBusy 18%, Occ 25%). Warmup still one 256-chunk: 0.9^256 ~ 2e-12.
#define CH     256
#define SEGCH  2
#define SEGLEN (CH * SEGCH)      // 512
#define SPR    (NN / SEGLEN)     // 625 (exact)
#define NBLK   (BB * SPR / 4)    // 2500

__global__ __launch_bounds__(256, 4) void compress_kernel(
    const float* __restrict__ enh_g, const float* __restrict__ noi_g,
    const float* __restrict__ ratio, float* __restrict__ out,
    unsigned* __restrict__ ws_u)
{
    const int lane = threadIdx.x & 63;
    const int wid  = blockIdx.x * 4 + (threadIdx.x >> 6);   // 0..9999
    const int row  = wid / SPR;
    const int seg  = wid - row * SPR;
    const int s0   = seg * SEGLEN;

    const float* __restrict__ enh  = enh_g + (size_t)row * NN;
    const float* __restrict__ noi  = noi_g + (size_t)row * NN;
    const float* __restrict__ rrow = ratio + row * TT;
    float* __restrict__ orow       = out   + (size_t)row * NN;

    // ---- preload ratio window (segment+warmup spans <=12 entries) ----
    const float bsrc = fmaf((float)(s0 - CH) + 0.5f, 0.0125f, -0.5f);
    int base = (int)floorf(bsrc);
    if (base < 0) base = 0;
    const float rv = rrow[min(base + lane, TT - 1)];

    // d_lane = 0.9^(4*lane)
    float d_lane = 1.f;
    if (lane & 1)  d_lane *= 0.65610000f;
    if (lane & 2)  d_lane *= 0.43046721f;
    if (lane & 4)  d_lane *= 0.18530202f;
    if (lane & 8)  d_lane *= 0.034336838f;
    if (lane & 16) d_lane *= 0.0011790185f;
    if (lane & 32) d_lane *= 1.3900845e-06f;

    // ---- preload warmup chunk ----
    const int p0w = s0 - CH + 4 * lane;
    const int pcw = p0w < 0 ? 0 : p0w;
    float4 e_cur = *(const float4*)(enh + pcw);
    float4 x_cur = *(const float4*)(noi + pcw);

    float s_e = 0.f, s_r = 0.f;
    float amax_c = 0.f, amax_e = 0.f;

    #pragma unroll
    for (int ci = 0; ci < SEGCH + 1; ++ci) {
        // prefetch next chunk (always in-bounds)
        float4 e_nxt, x_nxt;
        if (ci < SEGCH) {
            const int pn = s0 - CH + (ci + 1) * CH + 4 * lane;
            e_nxt = *(const float4*)(enh + pn);
            x_nxt = *(const float4*)(noi + pn);
        }

        const int cb = s0 - CH + ci * CH;     // chunk base (wave-uniform)
        const int p0 = cb + 4 * lane;

        // ---- per-sample gains + lane-local partials ----
        float pe[4], pr[4];
        float ge0 = 0.f, gr0 = 0.f;
        float ae = 0.f, ar = 0.f;
        #pragma unroll
        for (int k = 0; k < 4; ++k) {
            const float e   = (&e_cur.x)[k];
            const float x   = (&x_cur.x)[k];
            const float res = x - e;
            const int n  = p0 + k;
            const int nc = n < 0 ? 0 : n;
            float src = fmaf((float)nc + 0.5f, 0.0125f, -0.5f);
            src = fminf(fmaxf(src, 0.f), 3999.f);
            const int   i0 = (int)src;
            const float w  = src - (float)i0;
            const int   li0 = i0 - base;
            const int   li1 = min(i0 + 1, 3999) - base;
            const float r0 = __shfl(rv, li0, 64);
            const float r1 = __shfl(rv, li1, 64);
            const float rr = r0 * (1.f - w) + r1 * w;
            const float rcp_rr = __builtin_amdgcn_rcpf(rr);

            const float env_e = fabsf(e);
            const float gre = (env_e > 0.3f) ? fmaf(env_e - 0.3f, rcp_rr, 0.3f) : env_e;
            const float ge  = fminf(fmaxf(gre * __builtin_amdgcn_rcpf(env_e + 1e-8f), 0.1f), 2.f);
            const float env_r = fabsf(res);
            const float grr = (env_r > 0.1f) ? fmaf(env_r - 0.1f, 2.f * rcp_rr, 0.1f) : env_r;
            const float gr  = fminf(fmaxf(grr * __builtin_amdgcn_rcpf(env_r + 1e-8f), 0.1f), 2.f);

            if (k == 0) { ge0 = ge; gr0 = gr; }
            ae = fmaf(0.9f, ae, 0.1f * ge);
            ar = fmaf(0.9f, ar, 0.1f * gr);
            pe[k] = ae; pr[k] = ar;
        }

        // ---- Kogge-Stone scan over lanes (constant-a: b-only) ----
        float Be = pe[3], Br = pr[3];
        #pragma unroll
        for (int l = 0; l < 6; ++l) {
            const int dlt = 1 << l;
            const float ml = (l == 0) ? 0.65610000f  :
                             (l == 1) ? 0.43046721f  :
                             (l == 2) ? 0.18530202f  :
                             (l == 3) ? 0.034336838f :
                             (l == 4) ? 0.0011790185f : 1.3900845e-06f;
            const float me  = (lane >= dlt) ? ml : 0.f;
            const float bse = __shfl_up(Be, dlt, 64);
            const float bsr = __shfl_up(Br, dlt, 64);
            Be = fmaf(me, bse, Be);
            Br = fmaf(me, bsr, Br);
        }
        float Ee = __shfl_up(Be, 1, 64); if (lane == 0) Ee = 0.f;
        float Er = __shfl_up(Br, 1, 64); if (lane == 0) Er = 0.f;

        // exact reset at global sample 0 (chunk starting at n=0)
        if (cb == 0) { s_e = __shfl(ge0, 0, 64); s_r = __shfl(gr0, 0, 64); }

        const float Se = fmaf(d_lane, s_e, Ee);
        const float Sr = fmaf(d_lane, s_r, Er);

        if (ci > 0) {   // stored chunk (wave-uniform branch)
            float4 o;
            #pragma unroll
            for (int k = 0; k < 4; ++k) {
                const float ck = (k == 0) ? 0.9f : (k == 1) ? 0.81f
                               : (k == 2) ? 0.729f : 0.6561f;
                const float sek = fmaf(ck, Se, pe[k]);
                const float srk = fmaf(ck, Sr, pr[k]);
                const float e   = (&e_cur.x)[k];
                const float res = (&x_cur.x)[k] - e;
                const float c   = fmaf(0.1f * res, srk, e * sek);
                (&o.x)[k] = c;
                amax_c = fmaxf(amax_c, fabsf(c));
                amax_e = fmaxf(amax_e, fabsf(e));
            }
            *(float4*)(orow + p0) = o;
        }

        const float b63e = __shfl(Be, 63, 64);
        const float b63r = __shfl(Br, 63, 64);
        s_e = fmaf(1.9287e-12f, s_e, b63e);
        s_r = fmaf(1.9287e-12f, s_r, b63r);
        e_cur = e_nxt; x_cur = x_nxt;
    }

    // ---- wave -> block -> global max reduction ----
    #pragma unroll
    for (int off = 32; off > 0; off >>= 1) {
        amax_c = fmaxf(amax_c, __shfl_xor(amax_c, off, 64));
        amax_e = fmaxf(amax_e, __shfl_xor(amax_e, off, 64));
    }
    __shared__ float red[8];
    const int wv = threadIdx.x >> 6, ln = threadIdx.x & 63;
    if (ln == 0) { red[wv] = amax_c; red[4 + wv] = amax_e; }
    __syncthreads();
    if (threadIdx.x == 0) {
        float mc = fmaxf(fmaxf(red[0], red[1]), fmaxf(red[2], red[3]));
        float me = fmaxf(fmaxf(red[4], red[5]), fmaxf(red[6], red[7]));
        atomicMax(ws_u + 0, __float_as_uint(mc));
        atomicMax(ws_u + 1, __float_as_uint(me));
    }
}

// ---------------- K3: in-place normalize --------------------------------
__global__ __launch_bounds__(256) void scale_kernel(float4* __restrict__ out4,
                                                    const unsigned* __restrict__ ws_u)
{
    const float mo = __uint_as_float(ws_u[0]);
    const float me = __uint_as_float(ws_u[1]);
    const float scale = me / (mo + 1e-8f);
    const size_t i = (size_t)blockIdx.x * 256 + threadIdx.x;
    float4 v = out4[i];
    v.x *= scale; v.y *= scale; v.z *= scale; v.w *= scale;
    out4[i] = v;
}

extern "C" void kernel_launch(void* const* d_in, const int* in_sizes, int n_in,
                              void* d_out, int out_size, void* d_ws, size_t ws_size,
                              hipStream_t stream) {
    const float* gru = (const float*)d_in[0];
    const float* enh = (const float*)d_in[1];
    const float* noi = (const float*)d_in[2];
    const float* W1  = (const float*)d_in[3];
    const float* b1  = (const float*)d_in[4];
    const float* a1  = (const float*)d_in[5];
    const float* W2  = (const float*)d_in[6];
    const float* b2  = (const float*)d_in[7];
    const float* a2  = (const float*)d_in[8];
    const float* W3  = (const float*)d_in[9];
    const float* b3  = (const float*)d_in[10];
    float* out = (float*)d_out;

    unsigned* ws_u = (unsigned*)d_ws;               // [0]=max|c|, [1]=max|e|
    float* ratio   = (float*)((char*)d_ws + 256);   // B*T floats

    mlp_kernel<<<(BB * TT) / 128, 256, 0, stream>>>(gru, W1, b1, a1, W2, b2, a2, W3, b3, ratio, ws_u);
    compress_kernel<<<NBLK, 256, 0, stream>>>(enh, noi, ratio, out, ws_u);
    scale_kernel<<<(BB * NN) / 4 / 256, 256, 0, stream>>>((float4*)out, ws_u);
}

// Round 7
// 174.093 us; speedup vs baseline: 2.0158x; 1.2459x over previous
//
#include <hip/hip_runtime.h>
#include <hip/hip_bf16.h>
#include <math.h>

// Problem constants (from reference)
#define GRU_H 256
#define H1D   128
#define H2D   64
#define BB    16
#define TT    4000
#define NN    320000   // T * HOP

typedef __attribute__((ext_vector_type(8))) short short8;
typedef __attribute__((ext_vector_type(4))) float f32x4;

static __device__ __forceinline__ unsigned short f2bf(float x) {
    unsigned u = __float_as_uint(x);
    return (unsigned short)((u + 0x7FFFu + ((u >> 16) & 1u)) >> 16);
}
static __device__ __forceinline__ float bf2f(unsigned short h) {
    return __uint_as_float(((unsigned)h) << 16);
}

// ws layout (uints): [0..1023]   = 64 c-max slots, stride 16 (one/cacheline)
//                    [1024..2047]= 64 e-max slots, stride 16
//                    byte 8192+  = ratio[B*T] floats
#define WS_ESLOT 1024

// ---------------- K1: bf16-MFMA MLP -> ratio[B*T] -----------------------
// (unchanged from R4/R6; block 0 zeroes the 8 KB atomic-slot region)
#define H1CH 4608   // 128*36
#define W2CH 2304   // 64*36
__global__ __launch_bounds__(256) void mlp_kernel(
    const float* __restrict__ gru, const float* __restrict__ W1,
    const float* __restrict__ b1,  const float* __restrict__ a1p,
    const float* __restrict__ W2,  const float* __restrict__ b2,
    const float* __restrict__ a2p, const float* __restrict__ W3,
    const float* __restrict__ b3,  float* __restrict__ ratio_out,
    unsigned* __restrict__ ws_u)
{
    __shared__ unsigned short smem[36864];
    __shared__ float w3f[64];
    unsigned short* As  = smem;
    unsigned short* Bs  = smem + 4608;
    unsigned short* h2s = smem;          // overlays As/Bs (safe: after layer 1)
    unsigned short* h1s = smem + 9216;
    unsigned short* W2s = smem + 27648;

    const int t    = threadIdx.x;
    const int wave = t >> 6, lane = t & 63;
    const int lr   = lane & 15, q = lane >> 4;
    const int m0   = blockIdx.x * 128;
    const float a1v = a1p[0], a2v = a2p[0];

    if (blockIdx.x == 0) {               // zero all atomic-max slots
        #pragma unroll
        for (int i = t; i < 2048; i += 256) ws_u[i] = 0u;
    }
    if (t < 64) w3f[t] = W3[2 * H2D + t];         // only row 2 of W3 is live

    // ================= layer 1: h1 = prelu(G @ W1^T + b1) ===============
    const int wr = wave >> 1;
    const int wc = wave & 1;
    f32x4 acc1[4][4];
    #pragma unroll
    for (int mi = 0; mi < 4; ++mi)
        #pragma unroll
        for (int ni = 0; ni < 4; ++ni) acc1[mi][ni] = (f32x4){0.f, 0.f, 0.f, 0.f};

    for (int kc = 0; kc < 8; ++kc) {
        const int k0 = kc * 32;
        __syncthreads();
        #pragma unroll
        for (int it = 0; it < 4; ++it) {
            const int idx = t + 256 * it;
            const int row = idx >> 3, c4 = idx & 7;
            float4 g = *(const float4*)(gru + (size_t)(m0 + row) * GRU_H + k0 + c4 * 4);
            ushort4 gh = {f2bf(g.x), f2bf(g.y), f2bf(g.z), f2bf(g.w)};
            *(ushort4*)(As + row * 36 + c4 * 4) = gh;
            float4 w = *(const float4*)(W1 + (size_t)row * GRU_H + k0 + c4 * 4);
            ushort4 wh = {f2bf(w.x), f2bf(w.y), f2bf(w.z), f2bf(w.w)};
            *(ushort4*)(Bs + row * 36 + c4 * 4) = wh;
        }
        __syncthreads();
        short8 af[4], bf[4];
        #pragma unroll
        for (int mi = 0; mi < 4; ++mi) {
            const unsigned short* p = As + (wr * 64 + mi * 16 + lr) * 36 + q * 8;
            ushort4 lo = *(const ushort4*)(p), hi = *(const ushort4*)(p + 4);
            af[mi] = (short8){(short)lo.x, (short)lo.y, (short)lo.z, (short)lo.w,
                              (short)hi.x, (short)hi.y, (short)hi.z, (short)hi.w};
        }
        #pragma unroll
        for (int ni = 0; ni < 4; ++ni) {
            const unsigned short* p = Bs + (wc * 64 + ni * 16 + lr) * 36 + q * 8;
            ushort4 lo = *(const ushort4*)(p), hi = *(const ushort4*)(p + 4);
            bf[ni] = (short8){(short)lo.x, (short)lo.y, (short)lo.z, (short)lo.w,
                              (short)hi.x, (short)hi.y, (short)hi.z, (short)hi.w};
        }
        #pragma unroll
        for (int mi = 0; mi < 4; ++mi)
            #pragma unroll
            for (int ni = 0; ni < 4; ++ni)
                acc1[mi][ni] = __builtin_amdgcn_mfma_f32_16x16x32_bf16(
                    af[mi], bf[ni], acc1[mi][ni], 0, 0, 0);
    }

    #pragma unroll
    for (int ni = 0; ni < 4; ++ni) {
        const int col = wc * 64 + ni * 16 + lr;
        const float bv = b1[col];
        unsigned short* dst = h1s + (col >> 5) * H1CH + (col & 31);
        #pragma unroll
        for (int mi = 0; mi < 4; ++mi) {
            const int rbase = wr * 64 + mi * 16 + q * 4;
            #pragma unroll
            for (int r = 0; r < 4; ++r) {
                float x = acc1[mi][ni][r] + bv;
                x = (x >= 0.f) ? x : a1v * x;
                dst[(rbase + r) * 36] = f2bf(x);
            }
        }
    }
    #pragma unroll
    for (int it = 0; it < 8; ++it) {
        const int idx = t + 256 * it;
        const int row = idx >> 5, c4 = idx & 31;
        float4 w = *(const float4*)(W2 + (size_t)row * H1D + c4 * 4);
        ushort4 wh = {f2bf(w.x), f2bf(w.y), f2bf(w.z), f2bf(w.w)};
        *(ushort4*)(W2s + (c4 >> 3) * W2CH + row * 36 + (c4 & 7) * 4) = wh;
    }
    __syncthreads();

    // ================= layer 2 ==========================================
    const int wr2 = wave >> 1;
    const int wc2 = wave & 1;
    f32x4 acc2[4][2];
    #pragma unroll
    for (int mi = 0; mi < 4; ++mi)
        #pragma unroll
        for (int ni = 0; ni < 2; ++ni) acc2[mi][ni] = (f32x4){0.f, 0.f, 0.f, 0.f};

    #pragma unroll
    for (int kc = 0; kc < 4; ++kc) {
        short8 af[4], bf[2];
        #pragma unroll
        for (int mi = 0; mi < 4; ++mi) {
            const unsigned short* p = h1s + kc * H1CH + (wr2 * 64 + mi * 16 + lr) * 36 + q * 8;
            ushort4 lo = *(const ushort4*)(p), hi = *(const ushort4*)(p + 4);
            af[mi] = (short8){(short)lo.x, (short)lo.y, (short)lo.z, (short)lo.w,
                              (short)hi.x, (short)hi.y, (short)hi.z, (short)hi.w};
        }
        #pragma unroll
        for (int ni = 0; ni < 2; ++ni) {
            const unsigned short* p = W2s + kc * W2CH + (wc2 * 32 + ni * 16 + lr) * 36 + q * 8;
            ushort4 lo = *(const ushort4*)(p), hi = *(const ushort4*)(p + 4);
            bf[ni] = (short8){(short)lo.x, (short)lo.y, (short)lo.z, (short)lo.w,
                              (short)hi.x, (short)hi.y, (short)hi.z, (short)hi.w};
        }
        #pragma unroll
        for (int mi = 0; mi < 4; ++mi)
            #pragma unroll
            for (int ni = 0; ni < 2; ++ni)
                acc2[mi][ni] = __builtin_amdgcn_mfma_f32_16x16x32_bf16(
                    af[mi], bf[ni], acc2[mi][ni], 0, 0, 0);
    }

    #pragma unroll
    for (int ni = 0; ni < 2; ++ni) {
        const int col = wc2 * 32 + ni * 16 + lr;
        const float bv = b2[col];
        unsigned short* dst = h2s + (col >> 5) * H1CH + (col & 31);
        #pragma unroll
        for (int mi = 0; mi < 4; ++mi) {
            const int rbase = wr2 * 64 + mi * 16 + q * 4;
            #pragma unroll
            for (int r = 0; r < 4; ++r) {
                float x = acc2[mi][ni][r] + bv;
                x = (x >= 0.f) ? x : a2v * x;
                dst[(rbase + r) * 36] = f2bf(x);
            }
        }
    }
    __syncthreads();

    // ================= layer 3 (p2 only) + softplus + clip ==============
    if (t < 128) {
        float p = b3[2];
        #pragma unroll
        for (int k = 0; k < 64; ++k)
            p = fmaf(bf2f(h2s[(k >> 5) * H1CH + t * 36 + (k & 31)]), w3f[k], p);
        float sp = fmaxf(p, 0.f) + log1pf(expf(-fabsf(p)));
        ratio_out[m0 + t] = fminf(sp + 1.0f, 20.0f);
    }
}

// ---------------- K2: wave-scan IIR compressor --------------------------
// R7: SEGCH back to 5 (R4's measured best), ratio back to hoistable global
// loads (R6's shfl-ratio lengthened the per-chunk critical path), keep the
// e/x chunk prefetch. Atomic maxes spread over 64 per-cacheline slots
// (R6 post-mortem: same-address device-scope RMWs serialize ~12 ns each —
// 5000 of them was the 37 µs regression).
#define CH     256
#define SEGCH  5
#define SEGLEN (CH * SEGCH)      // 1280
#define SPR    (NN / SEGLEN)     // 250 (exact)
#define NBLK   (BB * SPR / 4)    // 1000

__global__ __launch_bounds__(256, 4) void compress_kernel(
    const float* __restrict__ enh_g, const float* __restrict__ noi_g,
    const float* __restrict__ ratio, float* __restrict__ out,
    unsigned* __restrict__ ws_u)
{
    const int lane = threadIdx.x & 63;
    const int wid  = blockIdx.x * 4 + (threadIdx.x >> 6);   // 0..3999
    const int row  = wid / SPR;
    const int seg  = wid - row * SPR;
    const int s0   = seg * SEGLEN;

    const float* __restrict__ enh  = enh_g + (size_t)row * NN;
    const float* __restrict__ noi  = noi_g + (size_t)row * NN;
    const float* __restrict__ rrow = ratio + row * TT;
    float* __restrict__ orow       = out   + (size_t)row * NN;

    // d_lane = 0.9^(4*lane)
    float d_lane = 1.f;
    if (lane & 1)  d_lane *= 0.65610000f;
    if (lane & 2)  d_lane *= 0.43046721f;
    if (lane & 4)  d_lane *= 0.18530202f;
    if (lane & 8)  d_lane *= 0.034336838f;
    if (lane & 16) d_lane *= 0.0011790185f;
    if (lane & 32) d_lane *= 1.3900845e-06f;

    // ---- preload warmup chunk ----
    const int p0w = s0 - CH + 4 * lane;
    const int pcw = p0w < 0 ? 0 : p0w;
    float4 e_cur = *(const float4*)(enh + pcw);
    float4 x_cur = *(const float4*)(noi + pcw);

    float s_e = 0.f, s_r = 0.f;
    float amax_c = 0.f, amax_e = 0.f;

    #pragma unroll
    for (int ci = 0; ci < SEGCH + 1; ++ci) {
        // prefetch next chunk (always in-bounds)
        float4 e_nxt, x_nxt;
        if (ci < SEGCH) {
            const int pn = s0 - CH + (ci + 1) * CH + 4 * lane;
            e_nxt = *(const float4*)(enh + pn);
            x_nxt = *(const float4*)(noi + pn);
        }

        const int cb = s0 - CH + ci * CH;     // chunk base (wave-uniform)
        const int p0 = cb + 4 * lane;

        // ---- per-sample gains + lane-local partials ----
        float pe[4], pr[4];
        float ge0 = 0.f, gr0 = 0.f;
        float ae = 0.f, ar = 0.f;
        #pragma unroll
        for (int k = 0; k < 4; ++k) {
            const float e   = (&e_cur.x)[k];
            const float x   = (&x_cur.x)[k];
            const float res = x - e;
            const int n  = p0 + k;
            const int nc = n < 0 ? 0 : n;
            float src = fmaf((float)nc + 0.5f, 0.0125f, -0.5f);
            src = fminf(fmaxf(src, 0.f), 3999.f);
            const int   i0 = (int)src;
            const float w  = src - (float)i0;
            const int   i1 = min(i0 + 1, 3999);
            const float r0 = rrow[i0], r1 = rrow[i1];
            const float rr = r0 * (1.f - w) + r1 * w;
            const float rcp_rr = __builtin_amdgcn_rcpf(rr);

            const float env_e = fabsf(e);
            const float gre = (env_e > 0.3f) ? fmaf(env_e - 0.3f, rcp_rr, 0.3f) : env_e;
            const float ge  = fminf(fmaxf(gre * __builtin_amdgcn_rcpf(env_e + 1e-8f), 0.1f), 2.f);
            const float env_r = fabsf(res);
            const float grr = (env_r > 0.1f) ? fmaf(env_r - 0.1f, 2.f * rcp_rr, 0.1f) : env_r;
            const float gr  = fminf(fmaxf(grr * __builtin_amdgcn_rcpf(env_r + 1e-8f), 0.1f), 2.f);

            if (k == 0) { ge0 = ge; gr0 = gr; }
            ae = fmaf(0.9f, ae, 0.1f * ge);
            ar = fmaf(0.9f, ar, 0.1f * gr);
            pe[k] = ae; pr[k] = ar;
        }

        // ---- Kogge-Stone scan over lanes (constant-a: b-only) ----
        float Be = pe[3], Br = pr[3];
        #pragma unroll
        for (int l = 0; l < 6; ++l) {
            const int dlt = 1 << l;
            const float ml = (l == 0) ? 0.65610000f  :
                             (l == 1) ? 0.43046721f  :
                             (l == 2) ? 0.18530202f  :
                             (l == 3) ? 0.034336838f :
                             (l == 4) ? 0.0011790185f : 1.3900845e-06f;
            const float me  = (lane >= dlt) ? ml : 0.f;
            const float bse = __shfl_up(Be, dlt, 64);
            const float bsr = __shfl_up(Br, dlt, 64);
            Be = fmaf(me, bse, Be);
            Br = fmaf(me, bsr, Br);
        }
        float Ee = __shfl_up(Be, 1, 64); if (lane == 0) Ee = 0.f;
        float Er = __shfl_up(Br, 1, 64); if (lane == 0) Er = 0.f;

        // exact reset at global sample 0 (chunk starting at n=0)
        if (cb == 0) { s_e = __shfl(ge0, 0, 64); s_r = __shfl(gr0, 0, 64); }

        const float Se = fmaf(d_lane, s_e, Ee);
        const float Sr = fmaf(d_lane, s_r, Er);

        if (ci > 0) {   // stored chunk (wave-uniform branch)
            float4 o;
            #pragma unroll
            for (int k = 0; k < 4; ++k) {
                const float ck = (k == 0) ? 0.9f : (k == 1) ? 0.81f
                               : (k == 2) ? 0.729f : 0.6561f;
                const float sek = fmaf(ck, Se, pe[k]);
                const float srk = fmaf(ck, Sr, pr[k]);
                const float e   = (&e_cur.x)[k];
                const float res = (&x_cur.x)[k] - e;
                const float c   = fmaf(0.1f * res, srk, e * sek);
                (&o.x)[k] = c;
                amax_c = fmaxf(amax_c, fabsf(c));
                amax_e = fmaxf(amax_e, fabsf(e));
            }
            *(float4*)(orow + p0) = o;
        }

        const float b63e = __shfl(Be, 63, 64);
        const float b63r = __shfl(Br, 63, 64);
        s_e = fmaf(1.9287e-12f, s_e, b63e);
        s_r = fmaf(1.9287e-12f, s_r, b63r);
        e_cur = e_nxt; x_cur = x_nxt;
    }

    // ---- wave -> block -> slot-spread global max reduction ----
    #pragma unroll
    for (int off = 32; off > 0; off >>= 1) {
        amax_c = fmaxf(amax_c, __shfl_xor(amax_c, off, 64));
        amax_e = fmaxf(amax_e, __shfl_xor(amax_e, off, 64));
    }
    __shared__ float red[8];
    const int wv = threadIdx.x >> 6, ln = threadIdx.x & 63;
    if (ln == 0) { red[wv] = amax_c; red[4 + wv] = amax_e; }
    __syncthreads();
    if (threadIdx.x == 0) {
        float mc = fmaxf(fmaxf(red[0], red[1]), fmaxf(red[2], red[3]));
        float me = fmaxf(fmaxf(red[4], red[5]), fmaxf(red[6], red[7]));
        const int slot = (blockIdx.x & 63) * 16;   // one slot per cache line
        atomicMax(ws_u + slot, __float_as_uint(mc));
        atomicMax(ws_u + WS_ESLOT + slot, __float_as_uint(me));
    }
}

// ---------------- K3: reduce slots + in-place normalize -----------------
__global__ __launch_bounds__(256) void scale_kernel(float4* __restrict__ out4,
                                                    const unsigned* __restrict__ ws_u)
{
    const int lane = threadIdx.x & 63;
    float vc = __uint_as_float(ws_u[lane * 16]);
    float ve = __uint_as_float(ws_u[WS_ESLOT + lane * 16]);
    #pragma unroll
    for (int off = 32; off > 0; off >>= 1) {
        vc = fmaxf(vc, __shfl_xor(vc, off, 64));
        ve = fmaxf(ve, __shfl_xor(ve, off, 64));
    }
    const float scale = ve / (vc + 1e-8f);
    const size_t i = (size_t)blockIdx.x * 256 + threadIdx.x;
    float4 v = out4[i];
    v.x *= scale; v.y *= scale; v.z *= scale; v.w *= scale;
    out4[i] = v;
}

extern "C" void kernel_launch(void* const* d_in, const int* in_sizes, int n_in,
                              void* d_out, int out_size, void* d_ws, size_t ws_size,
                              hipStream_t stream) {
    const float* gru = (const float*)d_in[0];
    const float* enh = (const float*)d_in[1];
    const float* noi = (const float*)d_in[2];
    const float* W1  = (const float*)d_in[3];
    const float* b1  = (const float*)d_in[4];
    const float* a1  = (const float*)d_in[5];
    const float* W2  = (const float*)d_in[6];
    const float* b2  = (const float*)d_in[7];
    const float* a2  = (const float*)d_in[8];
    const float* W3  = (const float*)d_in[9];
    const float* b3  = (const float*)d_in[10];
    float* out = (float*)d_out;

    unsigned* ws_u = (unsigned*)d_ws;                 // 2048 uints of max-slots
    float* ratio   = (float*)((char*)d_ws + 8192);    // B*T floats

    mlp_kernel<<<(BB * TT) / 128, 256, 0, stream>>>(gru, W1, b1, a1, W2, b2, a2, W3, b3, ratio, ws_u);
    compress_kernel<<<NBLK, 256, 0, stream>>>(enh, noi, ratio, out, ws_u);
    scale_kernel<<<(BB * NN) / 4 / 256, 256, 0, stream>>>((float4*)out, ws_u);
}